// Round 7
// baseline (1403.369 us; speedup 1.0000x reference)
//
#include <hip/hip_runtime.h>
#include <hip/hip_bf16.h>

// Round 7: switch GEMMs to v_mfma_f32_32x32x16_bf16 (ceiling 2382-2495 TF vs
// 2075-2176 for 16x16x32; same LDS-read count per FLOP). Packs, staging,
// vmcnt ledgers, barriers: byte-identical to round 6 (proven). Only the
// fragment reads (32-row frags, k-half = lane>>5) and epilogues (32x32 C/D:
// col=lane&31, row=(reg&3)+8*(reg>>2)+4*(lane>>5)) change.
// Bank check: pos-group distribution for 32-row frag reads is uniform
// (8 lanes per 4-bank group) -> optimal, same as 16-row reads.

#define HDIM 4096
#define IDIM 11008
#define N2   22016
#define MTOK 2048
#define KT1  64      // HDIM/64
#define KT2  172     // IDIM/64
#define NB1  86      // IDIM/128
#define NB2  32      // HDIM/128
#define NKD  344     // 2*KT2: down K-steps of 32

typedef unsigned short ushort_t;
using f32x4  = __attribute__((ext_vector_type(4))) float;
using f32x16 = __attribute__((ext_vector_type(16))) float;
using bf16x8 = __attribute__((ext_vector_type(8))) short;
using u32x2  = __attribute__((ext_vector_type(2))) unsigned int;
using u32x4  = __attribute__((ext_vector_type(4))) unsigned int;

__device__ __forceinline__ unsigned int bf16rne(float f) {
    unsigned int u = __builtin_bit_cast(unsigned int, f);
    return (u + 0x7FFFu + ((u >> 16) & 1u)) >> 16;
}
__device__ __forceinline__ unsigned int pack2(float lo, float hi) {
    return bf16rne(lo) | (bf16rne(hi) << 16);
}
__device__ __forceinline__ void gl_lds16(const void* g, void* l) {
    __builtin_amdgcn_global_load_lds(
        (const __attribute__((address_space(1))) void*)g,
        (__attribute__((address_space(3))) void*)l, 16, 0, 0);
}

// ---------------- conversion kernels (unchanged, proven) ----------------

__global__ __launch_bounds__(256)
void conv_x(const float* __restrict__ X, ushort_t* __restrict__ XP) {
    int bid = blockIdx.x;
    int mb = bid >> 6, kt = bid & 63;
    int t = threadIdx.x;
    int r0 = t >> 4, c4 = t & 15;
    int kh = c4 >> 3, c = (c4 >> 1) & 3, lo4 = (c4 & 1) << 2;
    ushort_t* tp = XP + ((long)(mb >> 1) * KT1 + kt) * 16384 + (long)kh * 8192 + (mb & 1) * 4096;
#pragma unroll
    for (int p = 0; p < 8; ++p) {
        int rl = r0 + p * 16;
        f32x4 v = *(const f32x4*)(X + (long)(mb * 128 + rl) * HDIM + kt * 64 + c4 * 4);
        u32x2 pk = { pack2(v[0], v[1]), pack2(v[2], v[3]) };
        int q = rl >> 1;
        int pos = ((((rl & 1) << 2) | c) ^ (q & 7));
        *(u32x2*)&tp[q * 64 + pos * 8 + lo4] = pk;
    }
}

__global__ __launch_bounds__(256)
void conv_wgu(const float* __restrict__ W, ushort_t* __restrict__ WP) {
    int bid = blockIdx.x;
    int e = bid & 1, kt = (bid >> 1) & 63, nb = bid >> 7;
    int t = threadIdx.x;
    int kp = t >> 5, c4 = t & 31;
    const float* p = W + ((long)kt * 64 + kp * 8) * N2 + (long)e * IDIM + nb * 128 + c4 * 4;
    f32x4 v[8];
#pragma unroll
    for (int j = 0; j < 8; ++j) v[j] = *(const f32x4*)(p + (long)j * N2);
    ushort_t* tp = WP + ((long)nb * KT1 + kt) * 16384 + (long)(kp >> 2) * 8192 + e * 4096;
    int c = kp & 3;
#pragma unroll
    for (int cc = 0; cc < 4; ++cc) {
        int n = c4 * 4 + cc;
        int q = n >> 1;
        int pos = ((((n & 1) << 2) | c) ^ (q & 7));
        u32x4 pk = { pack2(v[0][cc], v[1][cc]), pack2(v[2][cc], v[3][cc]),
                     pack2(v[4][cc], v[5][cc]), pack2(v[6][cc], v[7][cc]) };
        *(u32x4*)&tp[q * 64 + pos * 8] = pk;
    }
}

__global__ __launch_bounds__(256)
void conv_wd2(const float* __restrict__ W, ushort_t* __restrict__ WPd) {
    int bid = blockIdx.x;
    int kt = bid % KT2, nb = bid / KT2;
    int t = threadIdx.x;
    int kp = t >> 5, c4 = t & 31;
    ushort_t* tp = WPd + ((long)nb * KT2 + kt) * 16384 + (long)(kp >> 2) * 8192;
    int c = kp & 3;
#pragma unroll
    for (int h = 0; h < 2; ++h) {
        const float* p = W + ((long)kt * 64 + kp * 8) * HDIM + nb * 256 + h * 128 + c4 * 4;
        f32x4 v[8];
#pragma unroll
        for (int j = 0; j < 8; ++j) v[j] = *(const f32x4*)(p + (long)j * HDIM);
#pragma unroll
        for (int cc = 0; cc < 4; ++cc) {
            int n = h * 128 + c4 * 4 + cc;
            int q = n >> 1;
            int pos = ((((n & 1) << 2) | c) ^ (q & 7));
            u32x4 pk = { pack2(v[0][cc], v[1][cc]), pack2(v[2][cc], v[3][cc]),
                         pack2(v[4][cc], v[5][cc]), pack2(v[6][cc], v[7][cc]) };
            *(u32x4*)&tp[q * 64 + pos * 8] = pk;
        }
    }
}

__global__ __launch_bounds__(256)
void conv_wd(const float* __restrict__ W, ushort_t* __restrict__ WP) {
    int bid = blockIdx.x;
    int kt = bid % KT2, nb = bid / KT2;
    int t = threadIdx.x;
    int kp = t >> 5, c4 = t & 31;
    const float* p = W + ((long)kt * 64 + kp * 8) * HDIM + nb * 128 + c4 * 4;
    f32x4 v[8];
#pragma unroll
    for (int j = 0; j < 8; ++j) v[j] = *(const f32x4*)(p + (long)j * HDIM);
    ushort_t* tp = WP + ((long)nb * KT2 + kt) * 8192 + (long)(kp >> 2) * 4096;
    int c = kp & 3;
#pragma unroll
    for (int cc = 0; cc < 4; ++cc) {
        int n = c4 * 4 + cc;
        int q = n >> 1;
        int pos = ((((n & 1) << 2) | c) ^ (q & 7));
        u32x4 pk = { pack2(v[0][cc], v[1][cc]), pack2(v[2][cc], v[3][cc]),
                     pack2(v[4][cc], v[5][cc]), pack2(v[6][cc], v[7][cc]) };
        *(u32x4*)&tp[q * 64 + pos * 8] = pk;
    }
}

#define STAGE_U(SRC, DSTOFF) do { \
    gl_lds16((SRC) + so + lane * 8, &lds[(DSTOFF) + so]); \
    gl_lds16((SRC) + 4096 + so + lane * 8, &lds[(DSTOFF) + 4096 + so]); } while (0)

#define MFMA16(ACC, AF, BF) \
    _Pragma("unroll") \
    for (int mf = 0; mf < 4; ++mf) \
        _Pragma("unroll") \
        for (int nf = 0; nf < 4; ++nf) \
            ACC[mf][nf] = __builtin_amdgcn_mfma_f32_16x16x32_bf16(AF[mf], BF[nf], ACC[mf][nf], 0, 0, 0);

#define VMCNT_MID(N) do { \
    if (pf) asm volatile("s_waitcnt vmcnt(" #N ")" ::: "memory"); \
    else    asm volatile("s_waitcnt vmcnt(0)" ::: "memory"); } while (0)
#define VMCNT_END(N) do { \
    if (pf) asm volatile("s_waitcnt vmcnt(" #N ")" ::: "memory"); } while (0)

// frag offset in a packed unit: row m (pair q=m>>1), k16-chunk c = ks*2 + (lane>>5)
__device__ __forceinline__ int frag_off(int m, int c) {
    int q = m >> 1;
    int pos = ((((m & 1) << 2) | c) ^ (q & 7));
    return q * 64 + pos * 8;
}

// ---------------- GEMM1: gate/up + silu, 32x32x16, 2 phases/K-tile ----------------
__global__ __launch_bounds__(512, 2)
void gu5_kernel(const ushort_t* __restrict__ XP, const ushort_t* __restrict__ WP,
                ushort_t* __restrict__ HP) {
    __shared__ ushort_t lds[65536];     // [2 buf][A0 | A1 | B0(g|u) | B1(g|u)]
    int nwg = gridDim.x;                // 688
    int cpx = nwg >> 3;
    int sw  = (blockIdx.x & 7) * cpx + (blockIdx.x >> 3);
    int mblk = sw & 7;
    int nblk = sw >> 3;
    const int t = threadIdx.x, lane = t & 63, w = t >> 6;
    const int wr = w >> 1, wc = w & 1;  // 4M x 2N waves, 64x64(+u) each
    const int l31 = lane & 31, l5 = lane >> 5;
    const int so = w * 512;

    int aoff[2][2], boff[2][2];
#pragma unroll
    for (int mi = 0; mi < 2; ++mi)
#pragma unroll
        for (int ks = 0; ks < 2; ++ks)
            aoff[mi][ks] = frag_off(wr * 64 + mi * 32 + l31, ks * 2 + l5);
#pragma unroll
    for (int ni = 0; ni < 2; ++ni)
#pragma unroll
        for (int ks = 0; ks < 2; ++ks)
            boff[ni][ks] = frag_off(wc * 64 + ni * 32 + l31, ks * 2 + l5);

    f32x16 accg[2][2] = {}, accu[2][2] = {};
    const ushort_t* srcA = XP + (long)mblk * KT1 * 16384;
    const ushort_t* srcB = WP + (long)nblk * KT1 * 16384;

    STAGE_U(srcA, 0);
    STAGE_U(srcB, 16384);
    STAGE_U(srcA + 8192, 8192);
    STAGE_U(srcB + 8192, 24576);
    asm volatile("s_waitcnt vmcnt(0)" ::: "memory");
    __builtin_amdgcn_s_barrier();

    int cur = 0;
    for (int kt = 0; kt < KT1; ++kt) {
        const int cb = cur * 32768, pb = (cur ^ 1) * 32768;
        const ushort_t* nA = srcA + (long)(kt + 1) * 16384;
        const ushort_t* nB = srcB + (long)(kt + 1) * 16384;
        const bool pf = (kt + 1 < KT1);
        bf16x8 af[2][2], bg[2][2], bu[2][2];

        // ---- phase 0: k 0..31 (unit A0/B0) ----
#pragma unroll
        for (int mi = 0; mi < 2; ++mi)
#pragma unroll
            for (int ks = 0; ks < 2; ++ks)
                af[mi][ks] = *(const bf16x8*)&lds[cb + aoff[mi][ks]];
#pragma unroll
        for (int ni = 0; ni < 2; ++ni)
#pragma unroll
            for (int ks = 0; ks < 2; ++ks) {
                bg[ni][ks] = *(const bf16x8*)&lds[cb + 16384 + boff[ni][ks]];
                bu[ni][ks] = *(const bf16x8*)&lds[cb + 16384 + 4096 + boff[ni][ks]];
            }
        if (pf) { STAGE_U(nA, pb); STAGE_U(nB, pb + 16384); }
        __builtin_amdgcn_s_barrier();
        __builtin_amdgcn_s_setprio(1);
#pragma unroll
        for (int ks = 0; ks < 2; ++ks)
#pragma unroll
            for (int mi = 0; mi < 2; ++mi)
#pragma unroll
                for (int ni = 0; ni < 2; ++ni) {
                    accg[mi][ni] = __builtin_amdgcn_mfma_f32_32x32x16_bf16(af[mi][ks], bg[ni][ks], accg[mi][ni], 0, 0, 0);
                    accu[mi][ni] = __builtin_amdgcn_mfma_f32_32x32x16_bf16(af[mi][ks], bu[ni][ks], accu[mi][ni], 0, 0, 0);
                }
        __builtin_amdgcn_s_setprio(0);
        VMCNT_MID(4);
        __builtin_amdgcn_s_barrier();

        // ---- phase 1: k 32..63 (unit A1/B1) ----
#pragma unroll
        for (int mi = 0; mi < 2; ++mi)
#pragma unroll
            for (int ks = 0; ks < 2; ++ks)
                af[mi][ks] = *(const bf16x8*)&lds[cb + 8192 + aoff[mi][ks]];
#pragma unroll
        for (int ni = 0; ni < 2; ++ni)
#pragma unroll
            for (int ks = 0; ks < 2; ++ks) {
                bg[ni][ks] = *(const bf16x8*)&lds[cb + 24576 + boff[ni][ks]];
                bu[ni][ks] = *(const bf16x8*)&lds[cb + 24576 + 4096 + boff[ni][ks]];
            }
        if (pf) { STAGE_U(nA + 8192, pb + 8192); STAGE_U(nB + 8192, pb + 24576); }
        __builtin_amdgcn_s_barrier();
        __builtin_amdgcn_s_setprio(1);
#pragma unroll
        for (int ks = 0; ks < 2; ++ks)
#pragma unroll
            for (int mi = 0; mi < 2; ++mi)
#pragma unroll
                for (int ni = 0; ni < 2; ++ni) {
                    accg[mi][ni] = __builtin_amdgcn_mfma_f32_32x32x16_bf16(af[mi][ks], bg[ni][ks], accg[mi][ni], 0, 0, 0);
                    accu[mi][ni] = __builtin_amdgcn_mfma_f32_32x32x16_bf16(af[mi][ks], bu[ni][ks], accu[mi][ni], 0, 0, 0);
                }
        __builtin_amdgcn_s_setprio(0);
        VMCNT_END(4);
        __builtin_amdgcn_s_barrier();

        cur ^= 1;
    }

    // epilogue: silu(g)*u -> HP packed tiles (32x32 C/D layout)
#pragma unroll
    for (int ni = 0; ni < 2; ++ni) {
        int nloc = wc * 64 + ni * 32 + l31;
        int kt2 = nblk * 2 + (nloc >> 6);
        int k = nloc & 63;
        int kh = k >> 5, c = (k >> 3) & 3, klow = k & 7;
        ushort_t* tp = HP + ((long)mblk * KT2 + kt2) * 16384 + kh * 8192 + klow;
#pragma unroll
        for (int mi = 0; mi < 2; ++mi)
#pragma unroll
            for (int reg = 0; reg < 16; ++reg) {
                int m = wr * 64 + mi * 32 + (reg & 3) + 8 * (reg >> 2) + 4 * l5;
                int q = m >> 1;
                int pos = ((((m & 1) << 2) | c) ^ (q & 7));
                float gv = accg[mi][ni][reg], uv = accu[mi][ni][reg];
                float s = gv / (1.0f + __expf(-gv));
                tp[q * 64 + pos * 8] = (ushort_t)bf16rne(s * uv);
            }
    }
}

// ---------------- GEMM2 tier-1: both experts, 256x256, ring-3, 32x32x16 ----------------
__global__ __launch_bounds__(512, 2)
void down5_kernel(const ushort_t* __restrict__ HP, const ushort_t* __restrict__ WPd,
                  float* __restrict__ Out) {
    __shared__ ushort_t lds[49152];     // ring-3 x [A-unit 8192 | B-unit 8192]
    int nwg = gridDim.x;                // 256
    int cpx = nwg >> 3;
    int sw  = (blockIdx.x & 7) * cpx + (blockIdx.x >> 3);
    int mblk = sw & 15;
    int nblk = sw >> 4;
    const int t = threadIdx.x, lane = t & 63, w = t >> 6;
    const int wr = w >> 2, wc = w & 3;  // 2M x 4N waves, per-wave 128x64
    const int l31 = lane & 31, l5 = lane >> 5;
    const int so = w * 512;

    int aoff[4][2], boff[2][2];
#pragma unroll
    for (int mi = 0; mi < 4; ++mi)
#pragma unroll
        for (int ks = 0; ks < 2; ++ks)
            aoff[mi][ks] = frag_off(wr * 128 + mi * 32 + l31, ks * 2 + l5);
#pragma unroll
    for (int ni = 0; ni < 2; ++ni)
#pragma unroll
        for (int ks = 0; ks < 2; ++ks)
            boff[ni][ks] = frag_off(wc * 64 + ni * 32 + l31, ks * 2 + l5);

    f32x16 acc[4][2] = {};
    const ushort_t* srcA = HP  + (long)mblk * KT2 * 16384;
    const ushort_t* srcB = WPd + (long)(((mblk >> 3) << 4) + nblk) * KT2 * 16384;

    STAGE_U(srcA, 0);
    STAGE_U(srcB, 8192);
    STAGE_U(srcA + 8192, 16384);
    STAGE_U(srcB + 8192, 16384 + 8192);
    asm volatile("s_waitcnt vmcnt(4)" ::: "memory");
    __builtin_amdgcn_s_barrier();

    int cb = 0, sb = 32768;
    for (int kt = 0; kt < NKD; ++kt) {
        bf16x8 af[4][2], bf[2][2];
#pragma unroll
        for (int mi = 0; mi < 4; ++mi)
#pragma unroll
            for (int ks = 0; ks < 2; ++ks)
                af[mi][ks] = *(const bf16x8*)&lds[cb + aoff[mi][ks]];
#pragma unroll
        for (int ni = 0; ni < 2; ++ni)
#pragma unroll
            for (int ks = 0; ks < 2; ++ks)
                bf[ni][ks] = *(const bf16x8*)&lds[cb + 8192 + boff[ni][ks]];
        const bool pf = (kt + 2 < NKD);
        if (pf) {
            const ushort_t* nA = srcA + (long)(kt + 2) * 8192;
            const ushort_t* nB = srcB + (long)(kt + 2) * 8192;
            STAGE_U(nA, sb);
            STAGE_U(nB, sb + 8192);
        }
        __builtin_amdgcn_s_barrier();
        __builtin_amdgcn_s_setprio(1);
#pragma unroll
        for (int ks = 0; ks < 2; ++ks)
#pragma unroll
            for (int mi = 0; mi < 4; ++mi)
#pragma unroll
                for (int ni = 0; ni < 2; ++ni)
                    acc[mi][ni] = __builtin_amdgcn_mfma_f32_32x32x16_bf16(af[mi][ks], bf[ni][ks], acc[mi][ni], 0, 0, 0);
        __builtin_amdgcn_s_setprio(0);
        if (pf)                   asm volatile("s_waitcnt vmcnt(4)" ::: "memory");
        else if (kt + 1 < NKD)    asm volatile("s_waitcnt vmcnt(0)" ::: "memory");
        __builtin_amdgcn_s_barrier();
        sb = cb;
        cb += 16384; if (cb == 49152) cb = 0;
    }

#pragma unroll
    for (int mi = 0; mi < 4; ++mi)
#pragma unroll
        for (int ni = 0; ni < 2; ++ni)
#pragma unroll
            for (int reg = 0; reg < 16; ++reg) {
                int m = mblk * 256 + wr * 128 + mi * 32 + (reg & 3) + 8 * (reg >> 2) + 4 * l5;
                int n = nblk * 256 + wc * 64 + ni * 32 + l31;
                Out[(long)m * HDIM + n] = acc[mi][ni][reg];
            }
}

// ---------------- GEMM2 tier-2: per-expert 256x128, 16x16 (round-4, proven) ----------------
__global__ __launch_bounds__(512, 2)
void down3_kernel(const ushort_t* __restrict__ HP, const ushort_t* __restrict__ WP,
                  float* __restrict__ Out) {
    __shared__ ushort_t lds[49152];
    int nwg = gridDim.x;
    int cpx = nwg >> 3;
    int sw  = (blockIdx.x & 7) * cpx + (blockIdx.x >> 3);
    int mblk = sw & 7;
    int nblk = sw >> 3;
    const int t = threadIdx.x, lane = t & 63, w = t >> 6;
    const int wr = w >> 1, wc = w & 1;
    const int rr = lane & 15, g4 = lane >> 4;
    const int so = w * 512;

    int aoff[4], boff[4];
#pragma unroll
    for (int mf = 0; mf < 4; ++mf) {
        int m = wr * 64 + mf * 16 + rr, q = m >> 1;
        aoff[mf] = q * 64 + ((((((m & 1) << 2) | g4) ^ (q & 7))) << 3);
    }
#pragma unroll
    for (int nf = 0; nf < 4; ++nf) {
        int n = wc * 64 + nf * 16 + rr, q = n >> 1;
        boff[nf] = q * 64 + ((((((n & 1) << 2) | g4) ^ (q & 7))) << 3);
    }

    f32x4 acc[4][4] = {};
    const ushort_t* srcA = HP + (long)mblk * KT2 * 16384;
    const ushort_t* srcB = WP + (long)nblk * KT2 * 8192;

    STAGE_U(srcA, 0);
    STAGE_U(srcA + 8192, 8192);
    STAGE_U(srcB, 16384);
    asm volatile("s_waitcnt vmcnt(0)" ::: "memory");
    __builtin_amdgcn_s_barrier();

    int cur = 0;
    for (int kt = 0; kt < KT2; ++kt) {
        const int cb = cur * 24576, pb = (cur ^ 1) * 24576;
        const ushort_t* nA = srcA + (long)(kt + 1) * 16384;
        const ushort_t* nB = srcB + (long)(kt + 1) * 8192;
        const bool pf = (kt + 1 < KT2);
        bf16x8 af[4], bfr[4];

#pragma unroll
        for (int mf = 0; mf < 4; ++mf) af[mf] = *(const bf16x8*)&lds[cb + aoff[mf]];
#pragma unroll
        for (int nf = 0; nf < 4; ++nf) bfr[nf] = *(const bf16x8*)&lds[cb + 16384 + boff[nf]];
        if (pf) { STAGE_U(nA, pb); STAGE_U(nB, pb + 16384); }
        __builtin_amdgcn_s_barrier();
        __builtin_amdgcn_s_setprio(1);
        MFMA16(acc, af, bfr);
        __builtin_amdgcn_s_setprio(0);
        VMCNT_MID(4);
        __builtin_amdgcn_s_barrier();

#pragma unroll
        for (int mf = 0; mf < 4; ++mf) af[mf] = *(const bf16x8*)&lds[cb + 8192 + aoff[mf]];
#pragma unroll
        for (int nf = 0; nf < 4; ++nf) bfr[nf] = *(const bf16x8*)&lds[cb + 20480 + boff[nf]];
        if (pf) STAGE_U(nA + 8192, pb + 8192);
        __builtin_amdgcn_s_barrier();
        __builtin_amdgcn_s_setprio(1);
        MFMA16(acc, af, bfr);
        __builtin_amdgcn_s_setprio(0);
        VMCNT_END(2);
        __builtin_amdgcn_s_barrier();

        cur ^= 1;
    }

#pragma unroll
    for (int mf = 0; mf < 4; ++mf)
#pragma unroll
        for (int nf = 0; nf < 4; ++nf)
#pragma unroll
            for (int i = 0; i < 4; ++i) {
                int m = mblk * 256 + wr * 64 + mf * 16 + g4 * 4 + i;
                int n = nblk * 128 + wc * 64 + nf * 16 + rr;
                Out[(long)m * HDIM + n] = acc[mf][nf][i];
            }
}

// ================= host =================
extern "C" void kernel_launch(void* const* d_in, const int* in_sizes, int n_in,
                              void* d_out, int out_size, void* d_ws, size_t ws_size,
                              hipStream_t stream) {
    const float* x     = (const float*)d_in[0];
    const float* Wgu_l = (const float*)d_in[3];
    const float* Wd_l  = (const float*)d_in[4];
    const float* Wgu_v = (const float*)d_in[5];
    const float* Wd_v  = (const float*)d_in[6];
    float* out         = (float*)d_out;

    const size_t XP_B  = (size_t)8 * KT1 * 32768;        //  16.8 MB
    const size_t HP_B  = (size_t)8 * KT2 * 32768;        //  45.1 MB (one expert)
    const size_t WP_B  = (size_t)NB1 * KT1 * 32768;      // 180.4 MB
    const size_t NEED1 = XP_B + 2 * HP_B + WP_B;         // 287.4 MB
    const size_t WD2_STRIDE = (size_t)16 * KT2 * 16384;  // expert stride in shorts (90.2 MB)

    if (ws_size >= NEED1) {
        ushort_t* XP = (ushort_t*)d_ws;
        ushort_t* HP = XP + XP_B / 2;
        ushort_t* WP = HP + HP_B;
        for (int e = 0; e < 2; ++e) {
            const float* xe = x + (long)e * MTOK * HDIM;
            conv_x  <<<dim3(16 * KT1),      dim3(256), 0, stream>>>(xe, XP);
            conv_wgu<<<dim3(NB1 * KT1 * 2), dim3(256), 0, stream>>>(e ? Wgu_v : Wgu_l, WP);
            gu5_kernel<<<dim3(8 * NB1),     dim3(512), 0, stream>>>(XP, WP, HP + (size_t)e * (HP_B / 2));
        }
        conv_wd2<<<dim3(16 * KT2), dim3(256), 0, stream>>>(Wd_l, WP);
        conv_wd2<<<dim3(16 * KT2), dim3(256), 0, stream>>>(Wd_v, WP + WD2_STRIDE);
        down5_kernel<<<dim3(256), dim3(512), 0, stream>>>(HP, WP, out);
    } else {
        ushort_t* XP = (ushort_t*)d_ws;
        ushort_t* HP = XP + XP_B / 2;
        ushort_t* WP = HP + HP_B / 2;
        for (int e = 0; e < 2; ++e) {
            const float* xe = x + (long)e * MTOK * HDIM;
            float*       oe = out + (long)e * MTOK * HDIM;
            conv_x  <<<dim3(16 * KT1),      dim3(256), 0, stream>>>(xe, XP);
            conv_wgu<<<dim3(NB1 * KT1 * 2), dim3(256), 0, stream>>>(e ? Wgu_v : Wgu_l, WP);
            gu5_kernel<<<dim3(8 * NB1),     dim3(512), 0, stream>>>(XP, WP, HP);
            conv_wd <<<dim3(NB2 * KT2),     dim3(256), 0, stream>>>(e ? Wd_v : Wd_l, WP);
            down3_kernel<<<dim3(8 * NB2),   dim3(512), 0, stream>>>(HP, WP, oe);
        }
    }
}

// Round 8
// 1378.116 us; speedup vs baseline: 1.0183x; 1.0183x over previous
//
#include <hip/hip_runtime.h>
#include <hip/hip_bf16.h>

// Round 8: revert cores to round-6 16x16x32 (32x32 frag reads caused 3.4e7 LDS
// bank conflicts -> reverted). Single change: gu11 = gu4 restructured to 64KB
// per-phase double-buffer (BK=32 slots) -> 2 blocks/CU (was 1 at 128KB), so two
// independent blocks overlap LDS bursts with MFMA (m114 mechanism). One barrier
// + vmcnt(0) per phase; staging a slot is safe because its readers drained at
// the previous phase's lgkmcnt(0), enforced for all waves by that phase's barrier.
// down4 (ring-3, both experts) and conv kernels byte-identical to round 6.

#define HDIM 4096
#define IDIM 11008
#define N2   22016
#define MTOK 2048
#define KT1  64      // HDIM/64
#define KT2  172     // IDIM/64
#define NB1  86      // IDIM/128
#define NB2  32      // HDIM/128
#define NKD  344     // 2*KT2: down K-steps of 32
#define NPG  128     // 2*KT1: gu K-steps of 32

typedef unsigned short ushort_t;
using f32x4  = __attribute__((ext_vector_type(4))) float;
using bf16x8 = __attribute__((ext_vector_type(8))) short;
using u32x2  = __attribute__((ext_vector_type(2))) unsigned int;
using u32x4  = __attribute__((ext_vector_type(4))) unsigned int;

__device__ __forceinline__ unsigned int bf16rne(float f) {
    unsigned int u = __builtin_bit_cast(unsigned int, f);
    return (u + 0x7FFFu + ((u >> 16) & 1u)) >> 16;
}
__device__ __forceinline__ unsigned int pack2(float lo, float hi) {
    return bf16rne(lo) | (bf16rne(hi) << 16);
}
__device__ __forceinline__ void gl_lds16(const void* g, void* l) {
    __builtin_amdgcn_global_load_lds(
        (const __attribute__((address_space(1))) void*)g,
        (__attribute__((address_space(3))) void*)l, 16, 0, 0);
}

// ---------------- conversion kernels (fp32 -> packed bf16 units, proven) ----------------

// x [2048][4096] -> XP [mb256(8)][kt(64)] 32KB tiles ([ks0 unit][ks1 unit])
__global__ __launch_bounds__(256)
void conv_x(const float* __restrict__ X, ushort_t* __restrict__ XP) {
    int bid = blockIdx.x;               // 16 mb128 * 64 kt
    int mb = bid >> 6, kt = bid & 63;
    int t = threadIdx.x;
    int r0 = t >> 4, c4 = t & 15;
    int kh = c4 >> 3, c = (c4 >> 1) & 3, lo4 = (c4 & 1) << 2;
    ushort_t* tp = XP + ((long)(mb >> 1) * KT1 + kt) * 16384 + (long)kh * 8192 + (mb & 1) * 4096;
#pragma unroll
    for (int p = 0; p < 8; ++p) {
        int rl = r0 + p * 16;
        f32x4 v = *(const f32x4*)(X + (long)(mb * 128 + rl) * HDIM + kt * 64 + c4 * 4);
        u32x2 pk = { pack2(v[0], v[1]), pack2(v[2], v[3]) };
        int q = rl >> 1;
        int pos = ((((rl & 1) << 2) | c) ^ (q & 7));
        *(u32x2*)&tp[q * 64 + pos * 8 + lo4] = pk;
    }
}

// Wgu [4096][22016] -> WP [(nb*64+kt)] 32KB tiles: [kh][g 4KB-sh | u 4KB-sh]
__global__ __launch_bounds__(256)
void conv_wgu(const float* __restrict__ W, ushort_t* __restrict__ WP) {
    int bid = blockIdx.x;               // nb(86)*kt(64)*e(2)
    int e = bid & 1, kt = (bid >> 1) & 63, nb = bid >> 7;
    int t = threadIdx.x;
    int kp = t >> 5, c4 = t & 31;
    const float* p = W + ((long)kt * 64 + kp * 8) * N2 + (long)e * IDIM + nb * 128 + c4 * 4;
    f32x4 v[8];
#pragma unroll
    for (int j = 0; j < 8; ++j) v[j] = *(const f32x4*)(p + (long)j * N2);
    ushort_t* tp = WP + ((long)nb * KT1 + kt) * 16384 + (long)(kp >> 2) * 8192 + e * 4096;
    int c = kp & 3;
#pragma unroll
    for (int cc = 0; cc < 4; ++cc) {
        int n = c4 * 4 + cc;
        int q = n >> 1;
        int pos = ((((n & 1) << 2) | c) ^ (q & 7));
        u32x4 pk = { pack2(v[0][cc], v[1][cc]), pack2(v[2][cc], v[3][cc]),
                     pack2(v[4][cc], v[5][cc]), pack2(v[6][cc], v[7][cc]) };
        *(u32x4*)&tp[q * 64 + pos * 8] = pk;
    }
}

// Wd [11008][4096] -> WPd2 256-col tiles [nb(16)][kt(172)] 32KB ([ks0][ks1]) (tier-1)
__global__ __launch_bounds__(256)
void conv_wd2(const float* __restrict__ W, ushort_t* __restrict__ WPd) {
    int bid = blockIdx.x;               // nb(16)*kt(172)
    int kt = bid % KT2, nb = bid / KT2;
    int t = threadIdx.x;
    int kp = t >> 5, c4 = t & 31;
    ushort_t* tp = WPd + ((long)nb * KT2 + kt) * 16384 + (long)(kp >> 2) * 8192;
    int c = kp & 3;
#pragma unroll
    for (int h = 0; h < 2; ++h) {
        const float* p = W + ((long)kt * 64 + kp * 8) * HDIM + nb * 256 + h * 128 + c4 * 4;
        f32x4 v[8];
#pragma unroll
        for (int j = 0; j < 8; ++j) v[j] = *(const f32x4*)(p + (long)j * HDIM);
#pragma unroll
        for (int cc = 0; cc < 4; ++cc) {
            int n = h * 128 + c4 * 4 + cc;
            int q = n >> 1;
            int pos = ((((n & 1) << 2) | c) ^ (q & 7));
            u32x4 pk = { pack2(v[0][cc], v[1][cc]), pack2(v[2][cc], v[3][cc]),
                         pack2(v[4][cc], v[5][cc]), pack2(v[6][cc], v[7][cc]) };
            *(u32x4*)&tp[q * 64 + pos * 8] = pk;
        }
    }
}

// Wd -> 128-col tiles [nb(32)][kt(172)] 16KB (tier-2 / down3)
__global__ __launch_bounds__(256)
void conv_wd(const float* __restrict__ W, ushort_t* __restrict__ WP) {
    int bid = blockIdx.x;               // nb(32)*kt(172)
    int kt = bid % KT2, nb = bid / KT2;
    int t = threadIdx.x;
    int kp = t >> 5, c4 = t & 31;
    const float* p = W + ((long)kt * 64 + kp * 8) * HDIM + nb * 128 + c4 * 4;
    f32x4 v[8];
#pragma unroll
    for (int j = 0; j < 8; ++j) v[j] = *(const f32x4*)(p + (long)j * HDIM);
    ushort_t* tp = WP + ((long)nb * KT2 + kt) * 8192 + (long)(kp >> 2) * 4096;
    int c = kp & 3;
#pragma unroll
    for (int cc = 0; cc < 4; ++cc) {
        int n = c4 * 4 + cc;
        int q = n >> 1;
        int pos = ((((n & 1) << 2) | c) ^ (q & 7));
        u32x4 pk = { pack2(v[0][cc], v[1][cc]), pack2(v[2][cc], v[3][cc]),
                     pack2(v[4][cc], v[5][cc]), pack2(v[6][cc], v[7][cc]) };
        *(u32x4*)&tp[q * 64 + pos * 8] = pk;
    }
}

// stage one 16KB unit (8192 shorts): 2 x global_load_lds per thread, linear dest
#define STAGE_U(SRC, DSTOFF) do { \
    gl_lds16((SRC) + so + lane * 8, &lds[(DSTOFF) + so]); \
    gl_lds16((SRC) + 4096 + so + lane * 8, &lds[(DSTOFF) + 4096 + so]); } while (0)

#define MFMA16(ACC, AF, BF) \
    _Pragma("unroll") \
    for (int mf = 0; mf < 4; ++mf) \
        _Pragma("unroll") \
        for (int nf = 0; nf < 4; ++nf) \
            ACC[mf][nf] = __builtin_amdgcn_mfma_f32_16x16x32_bf16(AF[mf], BF[nf], ACC[mf][nf], 0, 0, 0);

#define VMCNT_MID(N) do { \
    if (pf) asm volatile("s_waitcnt vmcnt(" #N ")" ::: "memory"); \
    else    asm volatile("s_waitcnt vmcnt(0)" ::: "memory"); } while (0)
#define VMCNT_END(N) do { \
    if (pf) asm volatile("s_waitcnt vmcnt(" #N ")" ::: "memory"); } while (0)

// ---------------- GEMM1: gate/up + silu, 64KB per-phase dbuf, 2 blocks/CU ----------------
__global__ __launch_bounds__(512, 2)
void gu11_kernel(const ushort_t* __restrict__ XP, const ushort_t* __restrict__ WP,
                 ushort_t* __restrict__ HP) {
    __shared__ ushort_t lds[32768];     // 64KB: [2 slot][A-unit 8192sh | B-unit(g|u) 8192sh]
    int nwg = gridDim.x;                // 688
    int cpx = nwg >> 3;
    int sw  = (blockIdx.x & 7) * cpx + (blockIdx.x >> 3);
    int mblk = sw & 7;                  // 0..7
    int nblk = sw >> 3;                 // 0..85
    const int t = threadIdx.x, lane = t & 63, w = t >> 6;
    const int wr = w >> 1, wc = w & 1;  // 4M x 2N waves
    const int rr = lane & 15, g4 = lane >> 4;
    const int so = w * 512;

    int aoff[4], boff[4];
#pragma unroll
    for (int mf = 0; mf < 4; ++mf) {
        int m = wr * 64 + mf * 16 + rr, q = m >> 1;
        aoff[mf] = q * 64 + ((((((m & 1) << 2) | g4) ^ (q & 7))) << 3);
    }
#pragma unroll
    for (int nf = 0; nf < 4; ++nf) {
        int n = wc * 64 + nf * 16 + rr, q = n >> 1;
        boff[nf] = q * 64 + ((((((n & 1) << 2) | g4) ^ (q & 7))) << 3);
    }

    f32x4 accg[4][4] = {}, accu[4][4] = {};
    // unit streams: XP tile = [A-k0|A-k1] per kt -> A-unit u at srcA + u*8192 (linear);
    // WP tile = [B-k0(g|u)|B-k1(g|u)] -> B-unit u at srcB + u*8192 (linear).
    const ushort_t* srcA = XP + (long)mblk * KT1 * 16384;
    const ushort_t* srcB = WP + (long)nblk * KT1 * 16384;

    // prologue: stage unit 0 into slot 0
    STAGE_U(srcA, 0);
    STAGE_U(srcB, 8192);
    asm volatile("s_waitcnt vmcnt(0)" ::: "memory");
    __builtin_amdgcn_s_barrier();

    for (int u = 0; u < NPG; ++u) {
        const int cb = (u & 1) << 14;   // *16384
        const int pb = cb ^ 16384;
        bf16x8 af[4], bg[4], bu[4];
        // reads of current slot (landed: prev phase's vmcnt(0)+barrier)
#pragma unroll
        for (int mf = 0; mf < 4; ++mf) af[mf] = *(const bf16x8*)&lds[cb + aoff[mf]];
#pragma unroll
        for (int nf = 0; nf < 4; ++nf) {
            bg[nf] = *(const bf16x8*)&lds[cb + 8192 + boff[nf]];
            bu[nf] = *(const bf16x8*)&lds[cb + 8192 + 4096 + boff[nf]];
        }
        // stage unit u+1 into other slot (its readers drained at phase u-1's
        // lgkmcnt(0), enforced for all waves by phase u-1's barrier)
        if (u + 1 < NPG) {
            const ushort_t* nA = srcA + (long)(u + 1) * 8192;
            const ushort_t* nB = srcB + (long)(u + 1) * 8192;
            STAGE_U(nA, pb);
            STAGE_U(nB, pb + 8192);
        }
        __builtin_amdgcn_s_setprio(1);
        MFMA16(accg, af, bg);           // compiler inserts lgkmcnt before first MFMA
        MFMA16(accu, af, bu);
        __builtin_amdgcn_s_setprio(0);
        asm volatile("s_waitcnt vmcnt(0)" ::: "memory");
        __builtin_amdgcn_s_barrier();
    }

    // epilogue: silu(g)*u -> HP packed tiles (identical to gu4)
#pragma unroll
    for (int nf = 0; nf < 4; ++nf) {
        int nloc = wc * 64 + nf * 16 + rr;
        int kt2 = nblk * 2 + (nloc >> 6);
        int k = nloc & 63;
        int kh = k >> 5, c = (k >> 3) & 3, klow = k & 7;
        ushort_t* tp = HP + ((long)mblk * KT2 + kt2) * 16384 + kh * 8192 + klow;
#pragma unroll
        for (int mf = 0; mf < 4; ++mf)
#pragma unroll
            for (int i = 0; i < 4; ++i) {
                int m = wr * 64 + mf * 16 + g4 * 4 + i;
                int q = m >> 1;
                int pos = ((((m & 1) << 2) | c) ^ (q & 7));
                float gv = accg[mf][nf][i], uv = accu[mf][nf][i];
                float s = gv / (1.0f + __expf(-gv));
                tp[q * 64 + pos * 8] = (ushort_t)bf16rne(s * uv);
            }
    }
}

// ---------------- GEMM2 tier-1: both experts, 256x256, ring-3 (round-6, proven) ----------------
__global__ __launch_bounds__(512, 2)
void down4_kernel(const ushort_t* __restrict__ HP, const ushort_t* __restrict__ WPd,
                  float* __restrict__ Out) {
    __shared__ ushort_t lds[49152];     // ring-3 x [A-unit 8192 | B-unit 8192]
    int nwg = gridDim.x;                // 256
    int cpx = nwg >> 3;
    int sw  = (blockIdx.x & 7) * cpx + (blockIdx.x >> 3);
    int mblk = sw & 15;                 // 0..15 (expert = mblk>>3)
    int nblk = sw >> 4;                 // 0..15
    const int t = threadIdx.x, lane = t & 63, w = t >> 6;
    const int wr = w >> 2, wc = w & 3;  // 2M x 4N waves, per-wave out 128x64
    const int rr = lane & 15, g4 = lane >> 4;
    const int so = w * 512;

    int aoff[8], boff[4];
#pragma unroll
    for (int mf = 0; mf < 8; ++mf) {
        int m = wr * 128 + mf * 16 + rr, q = m >> 1;
        aoff[mf] = q * 64 + ((((((m & 1) << 2) | g4) ^ (q & 7))) << 3);
    }
#pragma unroll
    for (int nf = 0; nf < 4; ++nf) {
        int n = wc * 64 + nf * 16 + rr, q = n >> 1;
        boff[nf] = q * 64 + ((((((n & 1) << 2) | g4) ^ (q & 7))) << 3);
    }

    f32x4 acc[8][4] = {};
    const ushort_t* srcA = HP  + (long)mblk * KT2 * 16384;
    const ushort_t* srcB = WPd + (long)(((mblk >> 3) << 4) + nblk) * KT2 * 16384;

    STAGE_U(srcA, 0);
    STAGE_U(srcB, 8192);
    STAGE_U(srcA + 8192, 16384);
    STAGE_U(srcB + 8192, 16384 + 8192);
    asm volatile("s_waitcnt vmcnt(4)" ::: "memory");
    __builtin_amdgcn_s_barrier();

    int cb = 0, sb = 32768;
    for (int kt = 0; kt < NKD; ++kt) {
        bf16x8 af[8], bf[4];
#pragma unroll
        for (int mf = 0; mf < 8; ++mf) af[mf] = *(const bf16x8*)&lds[cb + aoff[mf]];
#pragma unroll
        for (int nf = 0; nf < 4; ++nf) bf[nf] = *(const bf16x8*)&lds[cb + 8192 + boff[nf]];
        const bool pf = (kt + 2 < NKD);
        if (pf) {
            const ushort_t* nA = srcA + (long)(kt + 2) * 8192;
            const ushort_t* nB = srcB + (long)(kt + 2) * 8192;
            STAGE_U(nA, sb);
            STAGE_U(nB, sb + 8192);
        }
        __builtin_amdgcn_s_barrier();
        __builtin_amdgcn_s_setprio(1);
#pragma unroll
        for (int mf = 0; mf < 8; ++mf)
#pragma unroll
            for (int nf = 0; nf < 4; ++nf)
                acc[mf][nf] = __builtin_amdgcn_mfma_f32_16x16x32_bf16(af[mf], bf[nf], acc[mf][nf], 0, 0, 0);
        __builtin_amdgcn_s_setprio(0);
        if (pf)                   asm volatile("s_waitcnt vmcnt(4)" ::: "memory");
        else if (kt + 1 < NKD)    asm volatile("s_waitcnt vmcnt(0)" ::: "memory");
        __builtin_amdgcn_s_barrier();
        sb = cb;
        cb += 16384; if (cb == 49152) cb = 0;
    }

#pragma unroll
    for (int mf = 0; mf < 8; ++mf)
#pragma unroll
        for (int nf = 0; nf < 4; ++nf)
#pragma unroll
            for (int i = 0; i < 4; ++i) {
                int m = mblk * 256 + wr * 128 + mf * 16 + g4 * 4 + i;
                int n = nblk * 256 + wc * 64 + nf * 16 + rr;
                Out[(long)m * HDIM + n] = acc[mf][nf][i];
            }
}

// ---------------- GEMM2 tier-2: per-expert 256x128 (round-4, proven) ----------------
__global__ __launch_bounds__(512, 2)
void down3_kernel(const ushort_t* __restrict__ HP, const ushort_t* __restrict__ WP,
                  float* __restrict__ Out) {
    __shared__ ushort_t lds[49152];
    int nwg = gridDim.x;
    int cpx = nwg >> 3;
    int sw  = (blockIdx.x & 7) * cpx + (blockIdx.x >> 3);
    int mblk = sw & 7;
    int nblk = sw >> 3;
    const int t = threadIdx.x, lane = t & 63, w = t >> 6;
    const int wr = w >> 1, wc = w & 1;
    const int rr = lane & 15, g4 = lane >> 4;
    const int so = w * 512;

    int aoff[4], boff[4];
#pragma unroll
    for (int mf = 0; mf < 4; ++mf) {
        int m = wr * 64 + mf * 16 + rr, q = m >> 1;
        aoff[mf] = q * 64 + ((((((m & 1) << 2) | g4) ^ (q & 7))) << 3);
    }
#pragma unroll
    for (int nf = 0; nf < 4; ++nf) {
        int n = wc * 64 + nf * 16 + rr, q = n >> 1;
        boff[nf] = q * 64 + ((((((n & 1) << 2) | g4) ^ (q & 7))) << 3);
    }

    f32x4 acc[4][4] = {};
    const ushort_t* srcA = HP + (long)mblk * KT2 * 16384;
    const ushort_t* srcB = WP + (long)nblk * KT2 * 8192;

    STAGE_U(srcA, 0);
    STAGE_U(srcA + 8192, 8192);
    STAGE_U(srcB, 16384);
    asm volatile("s_waitcnt vmcnt(0)" ::: "memory");
    __builtin_amdgcn_s_barrier();

    int cur = 0;
    for (int kt = 0; kt < KT2; ++kt) {
        const int cb = cur * 24576, pb = (cur ^ 1) * 24576;
        const ushort_t* nA = srcA + (long)(kt + 1) * 16384;
        const ushort_t* nB = srcB + (long)(kt + 1) * 8192;
        const bool pf = (kt + 1 < KT2);
        bf16x8 af[4], bfr[4];

#pragma unroll
        for (int mf = 0; mf < 4; ++mf) af[mf] = *(const bf16x8*)&lds[cb + aoff[mf]];
#pragma unroll
        for (int nf = 0; nf < 4; ++nf) bfr[nf] = *(const bf16x8*)&lds[cb + 16384 + boff[nf]];
        if (pf) { STAGE_U(nA, pb); STAGE_U(nB, pb + 16384); }
        __builtin_amdgcn_s_barrier();
        __builtin_amdgcn_s_setprio(1);
        MFMA16(acc, af, bfr);
        __builtin_amdgcn_s_setprio(0);
        VMCNT_MID(4);
        __builtin_amdgcn_s_barrier();

#pragma unroll
        for (int mf = 0; mf < 4; ++mf) af[mf] = *(const bf16x8*)&lds[cb + 8192 + aoff[mf]];
#pragma unroll
        for (int nf = 0; nf < 4; ++nf) bfr[nf] = *(const bf16x8*)&lds[cb + 20480 + boff[nf]];
        if (pf) STAGE_U(nA + 8192, pb + 8192);
        __builtin_amdgcn_s_barrier();
        __builtin_amdgcn_s_setprio(1);
        MFMA16(acc, af, bfr);
        __builtin_amdgcn_s_setprio(0);
        VMCNT_END(2);
        __builtin_amdgcn_s_barrier();

        cur ^= 1;
    }

#pragma unroll
    for (int mf = 0; mf < 4; ++mf)
#pragma unroll
        for (int nf = 0; nf < 4; ++nf)
#pragma unroll
            for (int i = 0; i < 4; ++i) {
                int m = mblk * 256 + wr * 64 + mf * 16 + g4 * 4 + i;
                int n = nblk * 128 + wc * 64 + nf * 16 + rr;
                Out[(long)m * HDIM + n] = acc[mf][nf][i];
            }
}

// ================= host =================
extern "C" void kernel_launch(void* const* d_in, const int* in_sizes, int n_in,
                              void* d_out, int out_size, void* d_ws, size_t ws_size,
                              hipStream_t stream) {
    const float* x     = (const float*)d_in[0];
    const float* Wgu_l = (const float*)d_in[3];
    const float* Wd_l  = (const float*)d_in[4];
    const float* Wgu_v = (const float*)d_in[5];
    const float* Wd_v  = (const float*)d_in[6];
    float* out         = (float*)d_out;

    const size_t XP_B  = (size_t)8 * KT1 * 32768;        //  16.8 MB
    const size_t HP_B  = (size_t)8 * KT2 * 32768;        //  45.1 MB (one expert)
    const size_t WP_B  = (size_t)NB1 * KT1 * 32768;      // 180.4 MB
    const size_t NEED1 = XP_B + 2 * HP_B + WP_B;         // 287.4 MB
    const size_t WD2_STRIDE = (size_t)16 * KT2 * 16384;  // expert stride in shorts (90.2 MB)

    if (ws_size >= NEED1) {
        ushort_t* XP = (ushort_t*)d_ws;
        ushort_t* HP = XP + XP_B / 2;
        ushort_t* WP = HP + HP_B;
        for (int e = 0; e < 2; ++e) {
            const float* xe = x + (long)e * MTOK * HDIM;
            conv_x  <<<dim3(16 * KT1),      dim3(256), 0, stream>>>(xe, XP);
            conv_wgu<<<dim3(NB1 * KT1 * 2), dim3(256), 0, stream>>>(e ? Wgu_v : Wgu_l, WP);
            gu11_kernel<<<dim3(8 * NB1),    dim3(512), 0, stream>>>(XP, WP, HP + (size_t)e * (HP_B / 2));
        }
        conv_wd2<<<dim3(16 * KT2), dim3(256), 0, stream>>>(Wd_l, WP);
        conv_wd2<<<dim3(16 * KT2), dim3(256), 0, stream>>>(Wd_v, WP + WD2_STRIDE);
        down4_kernel<<<dim3(256), dim3(512), 0, stream>>>(HP, WP, out);
    } else {
        ushort_t* XP = (ushort_t*)d_ws;
        ushort_t* HP = XP + XP_B / 2;
        ushort_t* WP = HP + HP_B / 2;
        for (int e = 0; e < 2; ++e) {
            const float* xe = x + (long)e * MTOK * HDIM;
            float*       oe = out + (long)e * MTOK * HDIM;
            conv_x  <<<dim3(16 * KT1),      dim3(256), 0, stream>>>(xe, XP);
            conv_wgu<<<dim3(NB1 * KT1 * 2), dim3(256), 0, stream>>>(e ? Wgu_v : Wgu_l, WP);
            gu11_kernel<<<dim3(8 * NB1),    dim3(512), 0, stream>>>(XP, WP, HP);
            conv_wd <<<dim3(NB2 * KT2),     dim3(256), 0, stream>>>(e ? Wd_v : Wd_l, WP);
            down3_kernel<<<dim3(8 * NB2),   dim3(512), 0, stream>>>(HP, WP, oe);
        }
    }
}

// Round 9
// 1271.824 us; speedup vs baseline: 1.1034x; 1.0836x over previous
//
#include <hip/hip_runtime.h>
#include <hip/hip_bf16.h>

// Round 9: gu12 = gu with down4's EXACT ring-3 schedule (the measured-best core:
// down4 runs 52% MfmaUtil vs gu4's 46% at identical 12-ds_read:32-MFMA cadence).
// Ring-3 x [A-unit 16KB | B-unit(g|u) 16KB] = 96KB LDS, BK=32 steps, counted
// vmcnt(4) with 2-step load lead, vmcnt(0) only in the tail. Round-8's per-phase
// vmcnt(0) dbuf (gu11) regressed and is reverted. down4/down3/convs/host = round 6.

#define HDIM 4096
#define IDIM 11008
#define N2   22016
#define MTOK 2048
#define KT1  64      // HDIM/64
#define KT2  172     // IDIM/64
#define NB1  86      // IDIM/128
#define NB2  32      // HDIM/128
#define NKD  344     // 2*KT2: down K-steps of 32
#define NPG  128     // 2*KT1: gu K-steps of 32

typedef unsigned short ushort_t;
using f32x4  = __attribute__((ext_vector_type(4))) float;
using bf16x8 = __attribute__((ext_vector_type(8))) short;
using u32x2  = __attribute__((ext_vector_type(2))) unsigned int;
using u32x4  = __attribute__((ext_vector_type(4))) unsigned int;

__device__ __forceinline__ unsigned int bf16rne(float f) {
    unsigned int u = __builtin_bit_cast(unsigned int, f);
    return (u + 0x7FFFu + ((u >> 16) & 1u)) >> 16;
}
__device__ __forceinline__ unsigned int pack2(float lo, float hi) {
    return bf16rne(lo) | (bf16rne(hi) << 16);
}
__device__ __forceinline__ void gl_lds16(const void* g, void* l) {
    __builtin_amdgcn_global_load_lds(
        (const __attribute__((address_space(1))) void*)g,
        (__attribute__((address_space(3))) void*)l, 16, 0, 0);
}

// ---------------- conversion kernels (fp32 -> packed bf16 units, proven) ----------------

__global__ __launch_bounds__(256)
void conv_x(const float* __restrict__ X, ushort_t* __restrict__ XP) {
    int bid = blockIdx.x;               // 16 mb128 * 64 kt
    int mb = bid >> 6, kt = bid & 63;
    int t = threadIdx.x;
    int r0 = t >> 4, c4 = t & 15;
    int kh = c4 >> 3, c = (c4 >> 1) & 3, lo4 = (c4 & 1) << 2;
    ushort_t* tp = XP + ((long)(mb >> 1) * KT1 + kt) * 16384 + (long)kh * 8192 + (mb & 1) * 4096;
#pragma unroll
    for (int p = 0; p < 8; ++p) {
        int rl = r0 + p * 16;
        f32x4 v = *(const f32x4*)(X + (long)(mb * 128 + rl) * HDIM + kt * 64 + c4 * 4);
        u32x2 pk = { pack2(v[0], v[1]), pack2(v[2], v[3]) };
        int q = rl >> 1;
        int pos = ((((rl & 1) << 2) | c) ^ (q & 7));
        *(u32x2*)&tp[q * 64 + pos * 8 + lo4] = pk;
    }
}

__global__ __launch_bounds__(256)
void conv_wgu(const float* __restrict__ W, ushort_t* __restrict__ WP) {
    int bid = blockIdx.x;               // nb(86)*kt(64)*e(2)
    int e = bid & 1, kt = (bid >> 1) & 63, nb = bid >> 7;
    int t = threadIdx.x;
    int kp = t >> 5, c4 = t & 31;
    const float* p = W + ((long)kt * 64 + kp * 8) * N2 + (long)e * IDIM + nb * 128 + c4 * 4;
    f32x4 v[8];
#pragma unroll
    for (int j = 0; j < 8; ++j) v[j] = *(const f32x4*)(p + (long)j * N2);
    ushort_t* tp = WP + ((long)nb * KT1 + kt) * 16384 + (long)(kp >> 2) * 8192 + e * 4096;
    int c = kp & 3;
#pragma unroll
    for (int cc = 0; cc < 4; ++cc) {
        int n = c4 * 4 + cc;
        int q = n >> 1;
        int pos = ((((n & 1) << 2) | c) ^ (q & 7));
        u32x4 pk = { pack2(v[0][cc], v[1][cc]), pack2(v[2][cc], v[3][cc]),
                     pack2(v[4][cc], v[5][cc]), pack2(v[6][cc], v[7][cc]) };
        *(u32x4*)&tp[q * 64 + pos * 8] = pk;
    }
}

__global__ __launch_bounds__(256)
void conv_wd2(const float* __restrict__ W, ushort_t* __restrict__ WPd) {
    int bid = blockIdx.x;               // nb(16)*kt(172)
    int kt = bid % KT2, nb = bid / KT2;
    int t = threadIdx.x;
    int kp = t >> 5, c4 = t & 31;
    ushort_t* tp = WPd + ((long)nb * KT2 + kt) * 16384 + (long)(kp >> 2) * 8192;
    int c = kp & 3;
#pragma unroll
    for (int h = 0; h < 2; ++h) {
        const float* p = W + ((long)kt * 64 + kp * 8) * HDIM + nb * 256 + h * 128 + c4 * 4;
        f32x4 v[8];
#pragma unroll
        for (int j = 0; j < 8; ++j) v[j] = *(const f32x4*)(p + (long)j * HDIM);
#pragma unroll
        for (int cc = 0; cc < 4; ++cc) {
            int n = h * 128 + c4 * 4 + cc;
            int q = n >> 1;
            int pos = ((((n & 1) << 2) | c) ^ (q & 7));
            u32x4 pk = { pack2(v[0][cc], v[1][cc]), pack2(v[2][cc], v[3][cc]),
                         pack2(v[4][cc], v[5][cc]), pack2(v[6][cc], v[7][cc]) };
            *(u32x4*)&tp[q * 64 + pos * 8] = pk;
        }
    }
}

__global__ __launch_bounds__(256)
void conv_wd(const float* __restrict__ W, ushort_t* __restrict__ WP) {
    int bid = blockIdx.x;               // nb(32)*kt(172)
    int kt = bid % KT2, nb = bid / KT2;
    int t = threadIdx.x;
    int kp = t >> 5, c4 = t & 31;
    const float* p = W + ((long)kt * 64 + kp * 8) * HDIM + nb * 128 + c4 * 4;
    f32x4 v[8];
#pragma unroll
    for (int j = 0; j < 8; ++j) v[j] = *(const f32x4*)(p + (long)j * HDIM);
    ushort_t* tp = WP + ((long)nb * KT2 + kt) * 8192 + (long)(kp >> 2) * 4096;
    int c = kp & 3;
#pragma unroll
    for (int cc = 0; cc < 4; ++cc) {
        int n = c4 * 4 + cc;
        int q = n >> 1;
        int pos = ((((n & 1) << 2) | c) ^ (q & 7));
        u32x4 pk = { pack2(v[0][cc], v[1][cc]), pack2(v[2][cc], v[3][cc]),
                     pack2(v[4][cc], v[5][cc]), pack2(v[6][cc], v[7][cc]) };
        *(u32x4*)&tp[q * 64 + pos * 8] = pk;
    }
}

// stage one 16KB unit (8192 shorts): 2 x global_load_lds per thread, linear dest
#define STAGE_U(SRC, DSTOFF) do { \
    gl_lds16((SRC) + so + lane * 8, &lds[(DSTOFF) + so]); \
    gl_lds16((SRC) + 4096 + so + lane * 8, &lds[(DSTOFF) + 4096 + so]); } while (0)

#define MFMA16(ACC, AF, BF) \
    _Pragma("unroll") \
    for (int mf = 0; mf < 4; ++mf) \
        _Pragma("unroll") \
        for (int nf = 0; nf < 4; ++nf) \
            ACC[mf][nf] = __builtin_amdgcn_mfma_f32_16x16x32_bf16(AF[mf], BF[nf], ACC[mf][nf], 0, 0, 0);

#define VMCNT_MID(N) do { \
    if (pf) asm volatile("s_waitcnt vmcnt(" #N ")" ::: "memory"); \
    else    asm volatile("s_waitcnt vmcnt(0)" ::: "memory"); } while (0)
#define VMCNT_END(N) do { \
    if (pf) asm volatile("s_waitcnt vmcnt(" #N ")" ::: "memory"); } while (0)

// ---------------- GEMM1: gate/up + silu, ring-3 BK=32 (down4 schedule) ----------------
__global__ __launch_bounds__(512, 2)
void gu12_kernel(const ushort_t* __restrict__ XP, const ushort_t* __restrict__ WP,
                 ushort_t* __restrict__ HP) {
    __shared__ ushort_t lds[49152];     // ring-3 x [A-unit 8192sh | B-unit(g|u) 8192sh]
    int nwg = gridDim.x;                // 688
    int cpx = nwg >> 3;
    int sw  = (blockIdx.x & 7) * cpx + (blockIdx.x >> 3);
    int mblk = sw & 7;                  // 0..7
    int nblk = sw >> 3;                 // 0..85
    const int t = threadIdx.x, lane = t & 63, w = t >> 6;
    const int wr = w >> 1, wc = w & 1;  // 4M x 2N waves
    const int rr = lane & 15, g4 = lane >> 4;
    const int so = w * 512;

    int aoff[4], boff[4];
#pragma unroll
    for (int mf = 0; mf < 4; ++mf) {
        int m = wr * 64 + mf * 16 + rr, q = m >> 1;
        aoff[mf] = q * 64 + ((((((m & 1) << 2) | g4) ^ (q & 7))) << 3);
    }
#pragma unroll
    for (int nf = 0; nf < 4; ++nf) {
        int n = wc * 64 + nf * 16 + rr, q = n >> 1;
        boff[nf] = q * 64 + ((((((n & 1) << 2) | g4) ^ (q & 7))) << 3);
    }

    f32x4 accg[4][4] = {}, accu[4][4] = {};
    // linear unit streams: A-unit u at srcA + u*8192; B-unit u (g 4096sh | u 4096sh)
    // at srcB + u*8192.
    const ushort_t* srcA = XP + (long)mblk * KT1 * 16384;
    const ushort_t* srcB = WP + (long)nblk * KT1 * 16384;

    // prologue: stage unit 0 -> slot0, unit 1 -> slot1
    STAGE_U(srcA, 0);
    STAGE_U(srcB, 8192);
    STAGE_U(srcA + 8192, 16384);
    STAGE_U(srcB + 8192, 16384 + 8192);
    asm volatile("s_waitcnt vmcnt(4)" ::: "memory");   // unit 0 landed
    __builtin_amdgcn_s_barrier();

    int cb = 0, sb = 32768;
    for (int kt = 0; kt < NPG; ++kt) {
        bf16x8 af[4], bg[4], bu[4];
#pragma unroll
        for (int mf = 0; mf < 4; ++mf) af[mf] = *(const bf16x8*)&lds[cb + aoff[mf]];
#pragma unroll
        for (int nf = 0; nf < 4; ++nf) {
            bg[nf] = *(const bf16x8*)&lds[cb + 8192 + boff[nf]];
            bu[nf] = *(const bf16x8*)&lds[cb + 8192 + 4096 + boff[nf]];
        }
        const bool pf = (kt + 2 < NPG);
        if (pf) {
            const ushort_t* nA = srcA + (long)(kt + 2) * 8192;
            const ushort_t* nB = srcB + (long)(kt + 2) * 8192;
            STAGE_U(nA, sb);
            STAGE_U(nB, sb + 8192);
        }
        __builtin_amdgcn_s_barrier();
        __builtin_amdgcn_s_setprio(1);
        MFMA16(accg, af, bg);
        MFMA16(accu, af, bu);
        __builtin_amdgcn_s_setprio(0);
        if (pf)                   asm volatile("s_waitcnt vmcnt(4)" ::: "memory"); // unit kt+1 landed
        else if (kt + 1 < NPG)    asm volatile("s_waitcnt vmcnt(0)" ::: "memory"); // tail drain
        __builtin_amdgcn_s_barrier();
        sb = cb;
        cb += 16384; if (cb == 49152) cb = 0;
    }

    // epilogue: silu(g)*u -> HP packed tiles
#pragma unroll
    for (int nf = 0; nf < 4; ++nf) {
        int nloc = wc * 64 + nf * 16 + rr;
        int kt2 = nblk * 2 + (nloc >> 6);
        int k = nloc & 63;
        int kh = k >> 5, c = (k >> 3) & 3, klow = k & 7;
        ushort_t* tp = HP + ((long)mblk * KT2 + kt2) * 16384 + kh * 8192 + klow;
#pragma unroll
        for (int mf = 0; mf < 4; ++mf)
#pragma unroll
            for (int i = 0; i < 4; ++i) {
                int m = wr * 64 + mf * 16 + g4 * 4 + i;
                int q = m >> 1;
                int pos = ((((m & 1) << 2) | c) ^ (q & 7));
                float gv = accg[mf][nf][i], uv = accu[mf][nf][i];
                float s = gv / (1.0f + __expf(-gv));
                tp[q * 64 + pos * 8] = (ushort_t)bf16rne(s * uv);
            }
    }
}

// ---------------- GEMM2 tier-1: both experts, 256x256, ring-3 (round-6, proven) ----------------
__global__ __launch_bounds__(512, 2)
void down4_kernel(const ushort_t* __restrict__ HP, const ushort_t* __restrict__ WPd,
                  float* __restrict__ Out) {
    __shared__ ushort_t lds[49152];     // ring-3 x [A-unit 8192 | B-unit 8192]
    int nwg = gridDim.x;                // 256
    int cpx = nwg >> 3;
    int sw  = (blockIdx.x & 7) * cpx + (blockIdx.x >> 3);
    int mblk = sw & 15;                 // 0..15 (expert = mblk>>3)
    int nblk = sw >> 4;                 // 0..15
    const int t = threadIdx.x, lane = t & 63, w = t >> 6;
    const int wr = w >> 2, wc = w & 3;  // 2M x 4N waves, per-wave out 128x64
    const int rr = lane & 15, g4 = lane >> 4;
    const int so = w * 512;

    int aoff[8], boff[4];
#pragma unroll
    for (int mf = 0; mf < 8; ++mf) {
        int m = wr * 128 + mf * 16 + rr, q = m >> 1;
        aoff[mf] = q * 64 + ((((((m & 1) << 2) | g4) ^ (q & 7))) << 3);
    }
#pragma unroll
    for (int nf = 0; nf < 4; ++nf) {
        int n = wc * 64 + nf * 16 + rr, q = n >> 1;
        boff[nf] = q * 64 + ((((((n & 1) << 2) | g4) ^ (q & 7))) << 3);
    }

    f32x4 acc[8][4] = {};
    const ushort_t* srcA = HP  + (long)mblk * KT2 * 16384;
    const ushort_t* srcB = WPd + (long)(((mblk >> 3) << 4) + nblk) * KT2 * 16384;

    STAGE_U(srcA, 0);
    STAGE_U(srcB, 8192);
    STAGE_U(srcA + 8192, 16384);
    STAGE_U(srcB + 8192, 16384 + 8192);
    asm volatile("s_waitcnt vmcnt(4)" ::: "memory");
    __builtin_amdgcn_s_barrier();

    int cb = 0, sb = 32768;
    for (int kt = 0; kt < NKD; ++kt) {
        bf16x8 af[8], bf[4];
#pragma unroll
        for (int mf = 0; mf < 8; ++mf) af[mf] = *(const bf16x8*)&lds[cb + aoff[mf]];
#pragma unroll
        for (int nf = 0; nf < 4; ++nf) bf[nf] = *(const bf16x8*)&lds[cb + 8192 + boff[nf]];
        const bool pf = (kt + 2 < NKD);
        if (pf) {
            const ushort_t* nA = srcA + (long)(kt + 2) * 8192;
            const ushort_t* nB = srcB + (long)(kt + 2) * 8192;
            STAGE_U(nA, sb);
            STAGE_U(nB, sb + 8192);
        }
        __builtin_amdgcn_s_barrier();
        __builtin_amdgcn_s_setprio(1);
#pragma unroll
        for (int mf = 0; mf < 8; ++mf)
#pragma unroll
            for (int nf = 0; nf < 4; ++nf)
                acc[mf][nf] = __builtin_amdgcn_mfma_f32_16x16x32_bf16(af[mf], bf[nf], acc[mf][nf], 0, 0, 0);
        __builtin_amdgcn_s_setprio(0);
        if (pf)                   asm volatile("s_waitcnt vmcnt(4)" ::: "memory");
        else if (kt + 1 < NKD)    asm volatile("s_waitcnt vmcnt(0)" ::: "memory");
        __builtin_amdgcn_s_barrier();
        sb = cb;
        cb += 16384; if (cb == 49152) cb = 0;
    }

#pragma unroll
    for (int mf = 0; mf < 8; ++mf)
#pragma unroll
        for (int nf = 0; nf < 4; ++nf)
#pragma unroll
            for (int i = 0; i < 4; ++i) {
                int m = mblk * 256 + wr * 128 + mf * 16 + g4 * 4 + i;
                int n = nblk * 256 + wc * 64 + nf * 16 + rr;
                Out[(long)m * HDIM + n] = acc[mf][nf][i];
            }
}

// ---------------- GEMM2 tier-2: per-expert 256x128 (round-4, proven) ----------------
__global__ __launch_bounds__(512, 2)
void down3_kernel(const ushort_t* __restrict__ HP, const ushort_t* __restrict__ WP,
                  float* __restrict__ Out) {
    __shared__ ushort_t lds[49152];
    int nwg = gridDim.x;
    int cpx = nwg >> 3;
    int sw  = (blockIdx.x & 7) * cpx + (blockIdx.x >> 3);
    int mblk = sw & 7;
    int nblk = sw >> 3;
    const int t = threadIdx.x, lane = t & 63, w = t >> 6;
    const int wr = w >> 1, wc = w & 1;
    const int rr = lane & 15, g4 = lane >> 4;
    const int so = w * 512;

    int aoff[4], boff[4];
#pragma unroll
    for (int mf = 0; mf < 4; ++mf) {
        int m = wr * 64 + mf * 16 + rr, q = m >> 1;
        aoff[mf] = q * 64 + ((((((m & 1) << 2) | g4) ^ (q & 7))) << 3);
    }
#pragma unroll
    for (int nf = 0; nf < 4; ++nf) {
        int n = wc * 64 + nf * 16 + rr, q = n >> 1;
        boff[nf] = q * 64 + ((((((n & 1) << 2) | g4) ^ (q & 7))) << 3);
    }

    f32x4 acc[4][4] = {};
    const ushort_t* srcA = HP + (long)mblk * KT2 * 16384;
    const ushort_t* srcB = WP + (long)nblk * KT2 * 8192;

    STAGE_U(srcA, 0);
    STAGE_U(srcA + 8192, 8192);
    STAGE_U(srcB, 16384);
    asm volatile("s_waitcnt vmcnt(0)" ::: "memory");
    __builtin_amdgcn_s_barrier();

    int cur = 0;
    for (int kt = 0; kt < KT2; ++kt) {
        const int cb = cur * 24576, pb = (cur ^ 1) * 24576;
        const ushort_t* nA = srcA + (long)(kt + 1) * 16384;
        const ushort_t* nB = srcB + (long)(kt + 1) * 8192;
        const bool pf = (kt + 1 < KT2);
        bf16x8 af[4], bfr[4];

#pragma unroll
        for (int mf = 0; mf < 4; ++mf) af[mf] = *(const bf16x8*)&lds[cb + aoff[mf]];
#pragma unroll
        for (int nf = 0; nf < 4; ++nf) bfr[nf] = *(const bf16x8*)&lds[cb + 16384 + boff[nf]];
        if (pf) { STAGE_U(nA, pb); STAGE_U(nB, pb + 16384); }
        __builtin_amdgcn_s_barrier();
        __builtin_amdgcn_s_setprio(1);
        MFMA16(acc, af, bfr);
        __builtin_amdgcn_s_setprio(0);
        VMCNT_MID(4);
        __builtin_amdgcn_s_barrier();

#pragma unroll
        for (int mf = 0; mf < 4; ++mf) af[mf] = *(const bf16x8*)&lds[cb + 8192 + aoff[mf]];
#pragma unroll
        for (int nf = 0; nf < 4; ++nf) bfr[nf] = *(const bf16x8*)&lds[cb + 20480 + boff[nf]];
        if (pf) STAGE_U(nA + 8192, pb + 8192);
        __builtin_amdgcn_s_barrier();
        __builtin_amdgcn_s_setprio(1);
        MFMA16(acc, af, bfr);
        __builtin_amdgcn_s_setprio(0);
        VMCNT_END(2);
        __builtin_amdgcn_s_barrier();

        cur ^= 1;
    }

#pragma unroll
    for (int mf = 0; mf < 4; ++mf)
#pragma unroll
        for (int nf = 0; nf < 4; ++nf)
#pragma unroll
            for (int i = 0; i < 4; ++i) {
                int m = mblk * 256 + wr * 64 + mf * 16 + g4 * 4 + i;
                int n = nblk * 128 + wc * 64 + nf * 16 + rr;
                Out[(long)m * HDIM + n] = acc[mf][nf][i];
            }
}

// ================= host =================
extern "C" void kernel_launch(void* const* d_in, const int* in_sizes, int n_in,
                              void* d_out, int out_size, void* d_ws, size_t ws_size,
                              hipStream_t stream) {
    const float* x     = (const float*)d_in[0];
    const float* Wgu_l = (const float*)d_in[3];
    const float* Wd_l  = (const float*)d_in[4];
    const float* Wgu_v = (const float*)d_in[5];
    const float* Wd_v  = (const float*)d_in[6];
    float* out         = (float*)d_out;

    const size_t XP_B  = (size_t)8 * KT1 * 32768;        //  16.8 MB
    const size_t HP_B  = (size_t)8 * KT2 * 32768;        //  45.1 MB (one expert)
    const size_t WP_B  = (size_t)NB1 * KT1 * 32768;      // 180.4 MB
    const size_t NEED1 = XP_B + 2 * HP_B + WP_B;         // 287.4 MB
    const size_t WD2_STRIDE = (size_t)16 * KT2 * 16384;  // expert stride in shorts (90.2 MB)

    if (ws_size >= NEED1) {
        ushort_t* XP = (ushort_t*)d_ws;
        ushort_t* HP = XP + XP_B / 2;
        ushort_t* WP = HP + HP_B;
        for (int e = 0; e < 2; ++e) {
            const float* xe = x + (long)e * MTOK * HDIM;
            conv_x  <<<dim3(16 * KT1),      dim3(256), 0, stream>>>(xe, XP);
            conv_wgu<<<dim3(NB1 * KT1 * 2), dim3(256), 0, stream>>>(e ? Wgu_v : Wgu_l, WP);
            gu12_kernel<<<dim3(8 * NB1),    dim3(512), 0, stream>>>(XP, WP, HP + (size_t)e * (HP_B / 2));
        }
        conv_wd2<<<dim3(16 * KT2), dim3(256), 0, stream>>>(Wd_l, WP);
        conv_wd2<<<dim3(16 * KT2), dim3(256), 0, stream>>>(Wd_v, WP + WD2_STRIDE);
        down4_kernel<<<dim3(256), dim3(512), 0, stream>>>(HP, WP, out);
    } else {
        ushort_t* XP = (ushort_t*)d_ws;
        ushort_t* HP = XP + XP_B / 2;
        ushort_t* WP = HP + HP_B / 2;
        for (int e = 0; e < 2; ++e) {
            const float* xe = x + (long)e * MTOK * HDIM;
            float*       oe = out + (long)e * MTOK * HDIM;
            conv_x  <<<dim3(16 * KT1),      dim3(256), 0, stream>>>(xe, XP);
            conv_wgu<<<dim3(NB1 * KT1 * 2), dim3(256), 0, stream>>>(e ? Wgu_v : Wgu_l, WP);
            gu12_kernel<<<dim3(8 * NB1),    dim3(512), 0, stream>>>(XP, WP, HP);
            conv_wd <<<dim3(NB2 * KT2),     dim3(256), 0, stream>>>(e ? Wd_v : Wd_l, WP);
            down3_kernel<<<dim3(8 * NB2),   dim3(512), 0, stream>>>(HP, WP, oe);
        }
    }
}

// Round 10
// 1223.473 us; speedup vs baseline: 1.1470x; 1.0395x over previous
//
#include <hip/hip_runtime.h>
#include <hip/hip_bf16.h>

// Round 10: single change vs round 9 — REMOVE the pre-MFMA barrier in both GEMM
// cores (gu13 = gu12 minus barrier1; down6 = down4 minus barrier1).
// Why: rounds 4/6/9 all sit at ~46% MfmaUtil (52% tail-adjusted) regardless of
// phase shape. Per-step per-CU: LDS reads ~1156 cyc vs MFMA ~1241 cyc, and the
// barrier between {reads+stage} and {MFMA} serializes them block-wide -> ~50%.
// With only the end-of-step barrier (vmcnt(4) then s_barrier), waves skew inside
// a step so wave A's MFMA overlaps wave B's ds_reads. Correctness audit:
//  (a) cross-wave staging visibility: vmcnt(4) + end barrier (unchanged);
//  (b) ring-3 WAR: slot re-staged at kt+2, after the end barrier its readers
//      passed post-MFMA (their lgkm-complete reads precede their barrier arrival).
// All packs/ledgers/epilogues/convs byte-identical to round 9.

#define HDIM 4096
#define IDIM 11008
#define N2   22016
#define MTOK 2048
#define KT1  64      // HDIM/64
#define KT2  172     // IDIM/64
#define NB1  86      // IDIM/128
#define NB2  32      // HDIM/128
#define NKD  344     // 2*KT2: down K-steps of 32
#define NPG  128     // 2*KT1: gu K-steps of 32

typedef unsigned short ushort_t;
using f32x4  = __attribute__((ext_vector_type(4))) float;
using bf16x8 = __attribute__((ext_vector_type(8))) short;
using u32x2  = __attribute__((ext_vector_type(2))) unsigned int;
using u32x4  = __attribute__((ext_vector_type(4))) unsigned int;

__device__ __forceinline__ unsigned int bf16rne(float f) {
    unsigned int u = __builtin_bit_cast(unsigned int, f);
    return (u + 0x7FFFu + ((u >> 16) & 1u)) >> 16;
}
__device__ __forceinline__ unsigned int pack2(float lo, float hi) {
    return bf16rne(lo) | (bf16rne(hi) << 16);
}
__device__ __forceinline__ void gl_lds16(const void* g, void* l) {
    __builtin_amdgcn_global_load_lds(
        (const __attribute__((address_space(1))) void*)g,
        (__attribute__((address_space(3))) void*)l, 16, 0, 0);
}

// ---------------- conversion kernels (fp32 -> packed bf16 units, proven) ----------------

__global__ __launch_bounds__(256)
void conv_x(const float* __restrict__ X, ushort_t* __restrict__ XP) {
    int bid = blockIdx.x;               // 16 mb128 * 64 kt
    int mb = bid >> 6, kt = bid & 63;
    int t = threadIdx.x;
    int r0 = t >> 4, c4 = t & 15;
    int kh = c4 >> 3, c = (c4 >> 1) & 3, lo4 = (c4 & 1) << 2;
    ushort_t* tp = XP + ((long)(mb >> 1) * KT1 + kt) * 16384 + (long)kh * 8192 + (mb & 1) * 4096;
#pragma unroll
    for (int p = 0; p < 8; ++p) {
        int rl = r0 + p * 16;
        f32x4 v = *(const f32x4*)(X + (long)(mb * 128 + rl) * HDIM + kt * 64 + c4 * 4);
        u32x2 pk = { pack2(v[0], v[1]), pack2(v[2], v[3]) };
        int q = rl >> 1;
        int pos = ((((rl & 1) << 2) | c) ^ (q & 7));
        *(u32x2*)&tp[q * 64 + pos * 8 + lo4] = pk;
    }
}

__global__ __launch_bounds__(256)
void conv_wgu(const float* __restrict__ W, ushort_t* __restrict__ WP) {
    int bid = blockIdx.x;               // nb(86)*kt(64)*e(2)
    int e = bid & 1, kt = (bid >> 1) & 63, nb = bid >> 7;
    int t = threadIdx.x;
    int kp = t >> 5, c4 = t & 31;
    const float* p = W + ((long)kt * 64 + kp * 8) * N2 + (long)e * IDIM + nb * 128 + c4 * 4;
    f32x4 v[8];
#pragma unroll
    for (int j = 0; j < 8; ++j) v[j] = *(const f32x4*)(p + (long)j * N2);
    ushort_t* tp = WP + ((long)nb * KT1 + kt) * 16384 + (long)(kp >> 2) * 8192 + e * 4096;
    int c = kp & 3;
#pragma unroll
    for (int cc = 0; cc < 4; ++cc) {
        int n = c4 * 4 + cc;
        int q = n >> 1;
        int pos = ((((n & 1) << 2) | c) ^ (q & 7));
        u32x4 pk = { pack2(v[0][cc], v[1][cc]), pack2(v[2][cc], v[3][cc]),
                     pack2(v[4][cc], v[5][cc]), pack2(v[6][cc], v[7][cc]) };
        *(u32x4*)&tp[q * 64 + pos * 8] = pk;
    }
}

__global__ __launch_bounds__(256)
void conv_wd2(const float* __restrict__ W, ushort_t* __restrict__ WPd) {
    int bid = blockIdx.x;               // nb(16)*kt(172)
    int kt = bid % KT2, nb = bid / KT2;
    int t = threadIdx.x;
    int kp = t >> 5, c4 = t & 31;
    ushort_t* tp = WPd + ((long)nb * KT2 + kt) * 16384 + (long)(kp >> 2) * 8192;
    int c = kp & 3;
#pragma unroll
    for (int h = 0; h < 2; ++h) {
        const float* p = W + ((long)kt * 64 + kp * 8) * HDIM + nb * 256 + h * 128 + c4 * 4;
        f32x4 v[8];
#pragma unroll
        for (int j = 0; j < 8; ++j) v[j] = *(const f32x4*)(p + (long)j * HDIM);
#pragma unroll
        for (int cc = 0; cc < 4; ++cc) {
            int n = h * 128 + c4 * 4 + cc;
            int q = n >> 1;
            int pos = ((((n & 1) << 2) | c) ^ (q & 7));
            u32x4 pk = { pack2(v[0][cc], v[1][cc]), pack2(v[2][cc], v[3][cc]),
                         pack2(v[4][cc], v[5][cc]), pack2(v[6][cc], v[7][cc]) };
            *(u32x4*)&tp[q * 64 + pos * 8] = pk;
        }
    }
}

__global__ __launch_bounds__(256)
void conv_wd(const float* __restrict__ W, ushort_t* __restrict__ WP) {
    int bid = blockIdx.x;               // nb(32)*kt(172)
    int kt = bid % KT2, nb = bid / KT2;
    int t = threadIdx.x;
    int kp = t >> 5, c4 = t & 31;
    const float* p = W + ((long)kt * 64 + kp * 8) * HDIM + nb * 128 + c4 * 4;
    f32x4 v[8];
#pragma unroll
    for (int j = 0; j < 8; ++j) v[j] = *(const f32x4*)(p + (long)j * HDIM);
    ushort_t* tp = WP + ((long)nb * KT2 + kt) * 8192 + (long)(kp >> 2) * 4096;
    int c = kp & 3;
#pragma unroll
    for (int cc = 0; cc < 4; ++cc) {
        int n = c4 * 4 + cc;
        int q = n >> 1;
        int pos = ((((n & 1) << 2) | c) ^ (q & 7));
        u32x4 pk = { pack2(v[0][cc], v[1][cc]), pack2(v[2][cc], v[3][cc]),
                     pack2(v[4][cc], v[5][cc]), pack2(v[6][cc], v[7][cc]) };
        *(u32x4*)&tp[q * 64 + pos * 8] = pk;
    }
}

// stage one 16KB unit (8192 shorts): 2 x global_load_lds per thread, linear dest
#define STAGE_U(SRC, DSTOFF) do { \
    gl_lds16((SRC) + so + lane * 8, &lds[(DSTOFF) + so]); \
    gl_lds16((SRC) + 4096 + so + lane * 8, &lds[(DSTOFF) + 4096 + so]); } while (0)

#define MFMA16(ACC, AF, BF) \
    _Pragma("unroll") \
    for (int mf = 0; mf < 4; ++mf) \
        _Pragma("unroll") \
        for (int nf = 0; nf < 4; ++nf) \
            ACC[mf][nf] = __builtin_amdgcn_mfma_f32_16x16x32_bf16(AF[mf], BF[nf], ACC[mf][nf], 0, 0, 0);

#define VMCNT_MID(N) do { \
    if (pf) asm volatile("s_waitcnt vmcnt(" #N ")" ::: "memory"); \
    else    asm volatile("s_waitcnt vmcnt(0)" ::: "memory"); } while (0)
#define VMCNT_END(N) do { \
    if (pf) asm volatile("s_waitcnt vmcnt(" #N ")" ::: "memory"); } while (0)

// ---------------- GEMM1: gate/up + silu, ring-3 BK=32, ONE barrier/step ----------------
__global__ __launch_bounds__(512, 2)
void gu13_kernel(const ushort_t* __restrict__ XP, const ushort_t* __restrict__ WP,
                 ushort_t* __restrict__ HP) {
    __shared__ ushort_t lds[49152];     // ring-3 x [A-unit 8192sh | B-unit(g|u) 8192sh]
    int nwg = gridDim.x;                // 688
    int cpx = nwg >> 3;
    int sw  = (blockIdx.x & 7) * cpx + (blockIdx.x >> 3);
    int mblk = sw & 7;                  // 0..7
    int nblk = sw >> 3;                 // 0..85
    const int t = threadIdx.x, lane = t & 63, w = t >> 6;
    const int wr = w >> 1, wc = w & 1;  // 4M x 2N waves
    const int rr = lane & 15, g4 = lane >> 4;
    const int so = w * 512;

    int aoff[4], boff[4];
#pragma unroll
    for (int mf = 0; mf < 4; ++mf) {
        int m = wr * 64 + mf * 16 + rr, q = m >> 1;
        aoff[mf] = q * 64 + ((((((m & 1) << 2) | g4) ^ (q & 7))) << 3);
    }
#pragma unroll
    for (int nf = 0; nf < 4; ++nf) {
        int n = wc * 64 + nf * 16 + rr, q = n >> 1;
        boff[nf] = q * 64 + ((((((n & 1) << 2) | g4) ^ (q & 7))) << 3);
    }

    f32x4 accg[4][4] = {}, accu[4][4] = {};
    const ushort_t* srcA = XP + (long)mblk * KT1 * 16384;
    const ushort_t* srcB = WP + (long)nblk * KT1 * 16384;

    // prologue: stage unit 0 -> slot0, unit 1 -> slot1
    STAGE_U(srcA, 0);
    STAGE_U(srcB, 8192);
    STAGE_U(srcA + 8192, 16384);
    STAGE_U(srcB + 8192, 16384 + 8192);
    asm volatile("s_waitcnt vmcnt(4)" ::: "memory");   // unit 0 landed
    __builtin_amdgcn_s_barrier();

    int cb = 0, sb = 32768;
    for (int kt = 0; kt < NPG; ++kt) {
        bf16x8 af[4], bg[4], bu[4];
#pragma unroll
        for (int mf = 0; mf < 4; ++mf) af[mf] = *(const bf16x8*)&lds[cb + aoff[mf]];
#pragma unroll
        for (int nf = 0; nf < 4; ++nf) {
            bg[nf] = *(const bf16x8*)&lds[cb + 8192 + boff[nf]];
            bu[nf] = *(const bf16x8*)&lds[cb + 8192 + 4096 + boff[nf]];
        }
        const bool pf = (kt + 2 < NPG);
        if (pf) {
            const ushort_t* nA = srcA + (long)(kt + 2) * 8192;
            const ushort_t* nB = srcB + (long)(kt + 2) * 8192;
            STAGE_U(nA, sb);
            STAGE_U(nB, sb + 8192);
        }
        // NO barrier here (round-10 change): waves skew, MFMA overlaps other waves' reads
        __builtin_amdgcn_s_setprio(1);
        MFMA16(accg, af, bg);
        MFMA16(accu, af, bu);
        __builtin_amdgcn_s_setprio(0);
        if (pf)                   asm volatile("s_waitcnt vmcnt(4)" ::: "memory"); // unit kt+1 landed
        else if (kt + 1 < NPG)    asm volatile("s_waitcnt vmcnt(0)" ::: "memory"); // tail drain
        __builtin_amdgcn_s_barrier();
        sb = cb;
        cb += 16384; if (cb == 49152) cb = 0;
    }

    // epilogue: silu(g)*u -> HP packed tiles
#pragma unroll
    for (int nf = 0; nf < 4; ++nf) {
        int nloc = wc * 64 + nf * 16 + rr;
        int kt2 = nblk * 2 + (nloc >> 6);
        int k = nloc & 63;
        int kh = k >> 5, c = (k >> 3) & 3, klow = k & 7;
        ushort_t* tp = HP + ((long)mblk * KT2 + kt2) * 16384 + kh * 8192 + klow;
#pragma unroll
        for (int mf = 0; mf < 4; ++mf)
#pragma unroll
            for (int i = 0; i < 4; ++i) {
                int m = wr * 64 + mf * 16 + g4 * 4 + i;
                int q = m >> 1;
                int pos = ((((m & 1) << 2) | c) ^ (q & 7));
                float gv = accg[mf][nf][i], uv = accu[mf][nf][i];
                float s = gv / (1.0f + __expf(-gv));
                tp[q * 64 + pos * 8] = (ushort_t)bf16rne(s * uv);
            }
    }
}

// ---------------- GEMM2 tier-1: both experts, 256x256, ring-3, ONE barrier/step ----------------
__global__ __launch_bounds__(512, 2)
void down6_kernel(const ushort_t* __restrict__ HP, const ushort_t* __restrict__ WPd,
                  float* __restrict__ Out) {
    __shared__ ushort_t lds[49152];     // ring-3 x [A-unit 8192 | B-unit 8192]
    int nwg = gridDim.x;                // 256
    int cpx = nwg >> 3;
    int sw  = (blockIdx.x & 7) * cpx + (blockIdx.x >> 3);
    int mblk = sw & 15;                 // 0..15 (expert = mblk>>3)
    int nblk = sw >> 4;                 // 0..15
    const int t = threadIdx.x, lane = t & 63, w = t >> 6;
    const int wr = w >> 2, wc = w & 3;  // 2M x 4N waves, per-wave out 128x64
    const int rr = lane & 15, g4 = lane >> 4;
    const int so = w * 512;

    int aoff[8], boff[4];
#pragma unroll
    for (int mf = 0; mf < 8; ++mf) {
        int m = wr * 128 + mf * 16 + rr, q = m >> 1;
        aoff[mf] = q * 64 + ((((((m & 1) << 2) | g4) ^ (q & 7))) << 3);
    }
#pragma unroll
    for (int nf = 0; nf < 4; ++nf) {
        int n = wc * 64 + nf * 16 + rr, q = n >> 1;
        boff[nf] = q * 64 + ((((((n & 1) << 2) | g4) ^ (q & 7))) << 3);
    }

    f32x4 acc[8][4] = {};
    const ushort_t* srcA = HP  + (long)mblk * KT2 * 16384;
    const ushort_t* srcB = WPd + (long)(((mblk >> 3) << 4) + nblk) * KT2 * 16384;

    STAGE_U(srcA, 0);
    STAGE_U(srcB, 8192);
    STAGE_U(srcA + 8192, 16384);
    STAGE_U(srcB + 8192, 16384 + 8192);
    asm volatile("s_waitcnt vmcnt(4)" ::: "memory");
    __builtin_amdgcn_s_barrier();

    int cb = 0, sb = 32768;
    for (int kt = 0; kt < NKD; ++kt) {
        bf16x8 af[8], bf[4];
#pragma unroll
        for (int mf = 0; mf < 8; ++mf) af[mf] = *(const bf16x8*)&lds[cb + aoff[mf]];
#pragma unroll
        for (int nf = 0; nf < 4; ++nf) bf[nf] = *(const bf16x8*)&lds[cb + 8192 + boff[nf]];
        const bool pf = (kt + 2 < NKD);
        if (pf) {
            const ushort_t* nA = srcA + (long)(kt + 2) * 8192;
            const ushort_t* nB = srcB + (long)(kt + 2) * 8192;
            STAGE_U(nA, sb);
            STAGE_U(nB, sb + 8192);
        }
        // NO barrier here (round-10 change)
        __builtin_amdgcn_s_setprio(1);
#pragma unroll
        for (int mf = 0; mf < 8; ++mf)
#pragma unroll
            for (int nf = 0; nf < 4; ++nf)
                acc[mf][nf] = __builtin_amdgcn_mfma_f32_16x16x32_bf16(af[mf], bf[nf], acc[mf][nf], 0, 0, 0);
        __builtin_amdgcn_s_setprio(0);
        if (pf)                   asm volatile("s_waitcnt vmcnt(4)" ::: "memory");
        else if (kt + 1 < NKD)    asm volatile("s_waitcnt vmcnt(0)" ::: "memory");
        __builtin_amdgcn_s_barrier();
        sb = cb;
        cb += 16384; if (cb == 49152) cb = 0;
    }

#pragma unroll
    for (int mf = 0; mf < 8; ++mf)
#pragma unroll
        for (int nf = 0; nf < 4; ++nf)
#pragma unroll
            for (int i = 0; i < 4; ++i) {
                int m = mblk * 256 + wr * 128 + mf * 16 + g4 * 4 + i;
                int n = nblk * 256 + wc * 64 + nf * 16 + rr;
                Out[(long)m * HDIM + n] = acc[mf][nf][i];
            }
}

// ---------------- GEMM2 tier-2: per-expert 256x128 (round-4, proven) ----------------
__global__ __launch_bounds__(512, 2)
void down3_kernel(const ushort_t* __restrict__ HP, const ushort_t* __restrict__ WP,
                  float* __restrict__ Out) {
    __shared__ ushort_t lds[49152];
    int nwg = gridDim.x;
    int cpx = nwg >> 3;
    int sw  = (blockIdx.x & 7) * cpx + (blockIdx.x >> 3);
    int mblk = sw & 7;
    int nblk = sw >> 3;
    const int t = threadIdx.x, lane = t & 63, w = t >> 6;
    const int wr = w >> 1, wc = w & 1;
    const int rr = lane & 15, g4 = lane >> 4;
    const int so = w * 512;

    int aoff[4], boff[4];
#pragma unroll
    for (int mf = 0; mf < 4; ++mf) {
        int m = wr * 64 + mf * 16 + rr, q = m >> 1;
        aoff[mf] = q * 64 + ((((((m & 1) << 2) | g4) ^ (q & 7))) << 3);
    }
#pragma unroll
    for (int nf = 0; nf < 4; ++nf) {
        int n = wc * 64 + nf * 16 + rr, q = n >> 1;
        boff[nf] = q * 64 + ((((((n & 1) << 2) | g4) ^ (q & 7))) << 3);
    }

    f32x4 acc[4][4] = {};
    const ushort_t* srcA = HP + (long)mblk * KT2 * 16384;
    const ushort_t* srcB = WP + (long)nblk * KT2 * 8192;

    STAGE_U(srcA, 0);
    STAGE_U(srcA + 8192, 8192);
    STAGE_U(srcB, 16384);
    asm volatile("s_waitcnt vmcnt(0)" ::: "memory");
    __builtin_amdgcn_s_barrier();

    int cur = 0;
    for (int kt = 0; kt < KT2; ++kt) {
        const int cb = cur * 24576, pb = (cur ^ 1) * 24576;
        const ushort_t* nA = srcA + (long)(kt + 1) * 16384;
        const ushort_t* nB = srcB + (long)(kt + 1) * 8192;
        const bool pf = (kt + 1 < KT2);
        bf16x8 af[4], bfr[4];

#pragma unroll
        for (int mf = 0; mf < 4; ++mf) af[mf] = *(const bf16x8*)&lds[cb + aoff[mf]];
#pragma unroll
        for (int nf = 0; nf < 4; ++nf) bfr[nf] = *(const bf16x8*)&lds[cb + 16384 + boff[nf]];
        if (pf) { STAGE_U(nA, pb); STAGE_U(nB, pb + 16384); }
        __builtin_amdgcn_s_barrier();
        __builtin_amdgcn_s_setprio(1);
        MFMA16(acc, af, bfr);
        __builtin_amdgcn_s_setprio(0);
        VMCNT_MID(4);
        __builtin_amdgcn_s_barrier();

#pragma unroll
        for (int mf = 0; mf < 4; ++mf) af[mf] = *(const bf16x8*)&lds[cb + 8192 + aoff[mf]];
#pragma unroll
        for (int nf = 0; nf < 4; ++nf) bfr[nf] = *(const bf16x8*)&lds[cb + 20480 + boff[nf]];
        if (pf) STAGE_U(nA + 8192, pb + 8192);
        __builtin_amdgcn_s_barrier();
        __builtin_amdgcn_s_setprio(1);
        MFMA16(acc, af, bfr);
        __builtin_amdgcn_s_setprio(0);
        VMCNT_END(2);
        __builtin_amdgcn_s_barrier();

        cur ^= 1;
    }

#pragma unroll
    for (int mf = 0; mf < 4; ++mf)
#pragma unroll
        for (int nf = 0; nf < 4; ++nf)
#pragma unroll
            for (int i = 0; i < 4; ++i) {
                int m = mblk * 256 + wr * 64 + mf * 16 + g4 * 4 + i;
                int n = nblk * 128 + wc * 64 + nf * 16 + rr;
                Out[(long)m * HDIM + n] = acc[mf][nf][i];
            }
}

// ================= host =================
extern "C" void kernel_launch(void* const* d_in, const int* in_sizes, int n_in,
                              void* d_out, int out_size, void* d_ws, size_t ws_size,
                              hipStream_t stream) {
    const float* x     = (const float*)d_in[0];
    const float* Wgu_l = (const float*)d_in[3];
    const float* Wd_l  = (const float*)d_in[4];
    const float* Wgu_v = (const float*)d_in[5];
    const float* Wd_v  = (const float*)d_in[6];
    float* out         = (float*)d_out;

    const size_t XP_B  = (size_t)8 * KT1 * 32768;        //  16.8 MB
    const size_t HP_B  = (size_t)8 * KT2 * 32768;        //  45.1 MB (one expert)
    const size_t WP_B  = (size_t)NB1 * KT1 * 32768;      // 180.4 MB
    const size_t NEED1 = XP_B + 2 * HP_B + WP_B;         // 287.4 MB
    const size_t WD2_STRIDE = (size_t)16 * KT2 * 16384;  // expert stride in shorts (90.2 MB)

    if (ws_size >= NEED1) {
        ushort_t* XP = (ushort_t*)d_ws;
        ushort_t* HP = XP + XP_B / 2;
        ushort_t* WP = HP + HP_B;
        for (int e = 0; e < 2; ++e) {
            const float* xe = x + (long)e * MTOK * HDIM;
            conv_x  <<<dim3(16 * KT1),      dim3(256), 0, stream>>>(xe, XP);
            conv_wgu<<<dim3(NB1 * KT1 * 2), dim3(256), 0, stream>>>(e ? Wgu_v : Wgu_l, WP);
            gu13_kernel<<<dim3(8 * NB1),    dim3(512), 0, stream>>>(XP, WP, HP + (size_t)e * (HP_B / 2));
        }
        conv_wd2<<<dim3(16 * KT2), dim3(256), 0, stream>>>(Wd_l, WP);
        conv_wd2<<<dim3(16 * KT2), dim3(256), 0, stream>>>(Wd_v, WP + WD2_STRIDE);
        down6_kernel<<<dim3(256), dim3(512), 0, stream>>>(HP, WP, out);
    } else {
        ushort_t* XP = (ushort_t*)d_ws;
        ushort_t* HP = XP + XP_B / 2;
        ushort_t* WP = HP + HP_B / 2;
        for (int e = 0; e < 2; ++e) {
            const float* xe = x + (long)e * MTOK * HDIM;
            float*       oe = out + (long)e * MTOK * HDIM;
            conv_x  <<<dim3(16 * KT1),      dim3(256), 0, stream>>>(xe, XP);
            conv_wgu<<<dim3(NB1 * KT1 * 2), dim3(256), 0, stream>>>(e ? Wgu_v : Wgu_l, WP);
            gu13_kernel<<<dim3(8 * NB1),    dim3(512), 0, stream>>>(XP, WP, HP);
            conv_wd <<<dim3(NB2 * KT2),     dim3(256), 0, stream>>>(e ? Wd_v : Wd_l, WP);
            down3_kernel<<<dim3(8 * NB2),   dim3(512), 0, stream>>>(HP, WP, oe);
        }
    }
}